// Round 10
// baseline (343.295 us; speedup 1.0000x reference)
//
#include <hip/hip_runtime.h>
#include <hip/hip_bf16.h>

#define NN 2048
#define QQ 9
#define DD 256
#define LL 4
#define BB 32
#define EE 32768
#define EPSV 1e-5f

typedef __attribute__((ext_vector_type(8))) short bf16x8;
typedef __attribute__((ext_vector_type(8))) ushort u16x8;
typedef __attribute__((ext_vector_type(4))) float f32x4;
typedef __attribute__((ext_vector_type(4))) int i32x4;

__device__ __forceinline__ ushort f2bf(float x)
{
    uint u = __float_as_uint(x);
    u += 0x7FFFu + ((u >> 16) & 1u);
    return (ushort)(u >> 16);
}
__device__ __forceinline__ float bf2f(ushort h)
{
    return __uint_as_float(((uint)h) << 16);
}

// ---------- CSR build ----------
__global__ void k_count(const int* __restrict__ src, int* __restrict__ cnt)
{
    int e = blockIdx.x * blockDim.x + threadIdx.x;
    if (e < EE) atomicAdd(&cnt[src[e]], 1);
}

__global__ __launch_bounds__(256) void k_scan(const int* __restrict__ cnt,
                                              int* __restrict__ row_ptr,
                                              int* __restrict__ cursor)
{
    __shared__ int part[256];
    int t = threadIdx.x;
    int local[8];
    int s = 0;
    #pragma unroll
    for (int i = 0; i < 8; ++i) { local[i] = cnt[t * 8 + i]; s += local[i]; }
    part[t] = s;
    __syncthreads();
    for (int off = 1; off < 256; off <<= 1) {
        int v = (t >= off) ? part[t - off] : 0;
        __syncthreads();
        part[t] += v;
        __syncthreads();
    }
    int run = part[t] - s;
    #pragma unroll
    for (int i = 0; i < 8; ++i) {
        int idx = t * 8 + i;
        row_ptr[idx] = run;
        cursor[idx]  = run;
        run += local[i];
    }
    if (t == 255) row_ptr[NN] = run;
}

__global__ void k_fill(const int* __restrict__ src, const int* __restrict__ dst,
                       int* __restrict__ cursor, int* __restrict__ col)
{
    int e = blockIdx.x * blockDim.x + threadIdx.x;
    if (e < EE) {
        int p = atomicAdd(&cursor[src[e]], 1);
        col[p] = dst[e];
    }
}

// ---------- h0 = bf16(batch with rows [0,Q) <- emotion_emb) ----------
__global__ void k_prep0(const float4* __restrict__ bf, const float4* __restrict__ emo,
                        ushort4* __restrict__ hhi)
{
    int total = BB * NN * (DD / 4);
    for (int idx = blockIdx.x * blockDim.x + threadIdx.x; idx < total;
         idx += gridDim.x * blockDim.x) {
        int d4 = idx & 63;
        int n  = (idx >> 6) & (NN - 1);
        float4 v = (n < QQ) ? emo[n * 64 + d4] : bf[idx];
        ushort4 h;
        h.x = f2bf(v.x); h.y = f2bf(v.y); h.z = f2bf(v.z); h.w = f2bf(v.w);
        hhi[idx] = h;
    }
}

// ---------- pooled = h + A.h : batch-paired gather (2 batches per wave) ----------
__global__ __launch_bounds__(256) void k_spmm6(
    const ushort* __restrict__ phi,
    const int* __restrict__ row_ptr, const int* __restrict__ col,
    ushort* __restrict__ ohi)
{
    int x     = blockIdx.x & 7;          // XCD slice: batches [4x, 4x+4)
    int local = blockIdx.x >> 3;
    int w     = threadIdx.x >> 6;
    int t     = threadIdx.x & 63;
    int inst  = local * 4 + w;           // [0, 4096): (pair-of-batches, node)
    int pl    = inst >> 11;              // 0/1: which batch pair in this XCD
    int n     = inst & (NN - 1);
    int b     = x * 4 + pl * 2 + (t >> 5);   // lanes 0-31: batch b0; 32-63: b0+1
    int q     = t & 31;                  // 16B chunk: elems [8q, 8q+8)
    const ushort* base = phi + (size_t)b * NN * DD + q * 8;

    u16x8 sv = *(const u16x8*)(base + (size_t)n * DD);
    float a[8];
    #pragma unroll
    for (int k = 0; k < 8; ++k) a[k] = bf2f((ushort)sv[k]);

    int beg = row_ptr[n], end = row_ptr[n + 1];
    int j = beg;
    for (; j < end && (j & 3); ++j) {
        u16x8 g = *(const u16x8*)(base + (size_t)col[j] * DD);
        #pragma unroll
        for (int k = 0; k < 8; ++k) a[k] += bf2f((ushort)g[k]);
    }
    for (; j + 8 <= end; j += 8) {
        i32x4 c0 = *(const i32x4*)(col + j);
        i32x4 c1 = *(const i32x4*)(col + j + 4);
        u16x8 g[8];
        g[0] = *(const u16x8*)(base + (size_t)c0.x * DD);
        g[1] = *(const u16x8*)(base + (size_t)c0.y * DD);
        g[2] = *(const u16x8*)(base + (size_t)c0.z * DD);
        g[3] = *(const u16x8*)(base + (size_t)c0.w * DD);
        g[4] = *(const u16x8*)(base + (size_t)c1.x * DD);
        g[5] = *(const u16x8*)(base + (size_t)c1.y * DD);
        g[6] = *(const u16x8*)(base + (size_t)c1.z * DD);
        g[7] = *(const u16x8*)(base + (size_t)c1.w * DD);
        #pragma unroll
        for (int u = 0; u < 8; ++u)
            #pragma unroll
            for (int k = 0; k < 8; ++k) a[k] += bf2f((ushort)g[u][k]);
    }
    if (j + 4 <= end) {
        i32x4 c = *(const i32x4*)(col + j);
        u16x8 g[4];
        g[0] = *(const u16x8*)(base + (size_t)c.x * DD);
        g[1] = *(const u16x8*)(base + (size_t)c.y * DD);
        g[2] = *(const u16x8*)(base + (size_t)c.z * DD);
        g[3] = *(const u16x8*)(base + (size_t)c.w * DD);
        #pragma unroll
        for (int u = 0; u < 4; ++u)
            #pragma unroll
            for (int k = 0; k < 8; ++k) a[k] += bf2f((ushort)g[u][k]);
        j += 4;
    }
    for (; j < end; ++j) {
        u16x8 g = *(const u16x8*)(base + (size_t)col[j] * DD);
        #pragma unroll
        for (int k = 0; k < 8; ++k) a[k] += bf2f((ushort)g[k]);
    }

    u16x8 o;
    #pragma unroll
    for (int k = 0; k < 8; ++k) o[k] = f2bf(a[k]);
    *(u16x8*)(ohi + ((size_t)b * NN + n) * DD + q * 8) = o;
}

// ---------- weight prep: Wt[mat][n][k] = bf16(W[mat][k][n]) ----------
__global__ __launch_bounds__(256) void k_wprep(const float* __restrict__ w1,
                                               const float* __restrict__ w2,
                                               ushort* __restrict__ wt_hi)
{
    __shared__ float tile[32][36];
    int bx = blockIdx.x;
    int mat = bx >> 6;
    int tt  = bx & 63;
    int tk = (tt >> 3) * 32;
    int tn = (tt & 7) * 32;
    const float* src = (mat < 4) ? (w1 + (size_t)mat * DD * DD)
                                 : (w2 + (size_t)(mat - 4) * DD * DD);
    int t = threadIdx.x;
    int r = t >> 3, c0 = (t & 7) * 4;
    float4 v = *(const float4*)(src + (size_t)(tk + r) * DD + tn + c0);
    tile[r][c0 + 0] = v.x; tile[r][c0 + 1] = v.y;
    tile[r][c0 + 2] = v.z; tile[r][c0 + 3] = v.w;
    __syncthreads();
    int nn = t >> 3, kq = (t & 7) * 4;
    ushort4 hh;
    hh.x = f2bf(tile[kq + 0][nn]); hh.y = f2bf(tile[kq + 1][nn]);
    hh.z = f2bf(tile[kq + 2][nn]); hh.w = f2bf(tile[kq + 3][nn]);
    size_t off = (size_t)mat * DD * DD + (size_t)(tn + nn) * DD + tk + kq;
    *(ushort4*)(wt_hi + off) = hh;
}

// ---------- fused layer GEMM: h = relu(bn2( relu(bn1(P@W1)) @ W2 )) ----------
// 64 rows x full N=256 per block; 8 waves (32m x 64n each); t lives in LDS only.
__global__ __launch_bounds__(512, 4) void k_gemm_fused(
    const ushort* __restrict__ A, const ushort* __restrict__ W1t,
    const ushort* __restrict__ W2t,
    const float* __restrict__ b1, const float* __restrict__ g1,
    const float* __restrict__ be1, const float* __restrict__ m1,
    const float* __restrict__ v1,
    const float* __restrict__ b2, const float* __restrict__ g2,
    const float* __restrict__ be2, const float* __restrict__ m2,
    const float* __restrict__ v2,
    ushort* __restrict__ O)
{
    __shared__ alignas(16) ushort As[64][40];    //  5,120 B
    __shared__ alignas(16) ushort Ws[256][40];   // 20,480 B
    __shared__ alignas(16) ushort Ts[64][264];   // 33,792 B  (t tile, 8-pad)

    int tid = threadIdx.x;
    int x  = blockIdx.x & 7;                 // XCD-aligned with spmm partition
    int lm = blockIdx.x >> 3;
    int m0 = x * 8192 + lm * 64;
    int lane = tid & 63;
    int w = tid >> 6;                        // 8 waves
    int wm = w & 1, wn = w >> 1;             // wave tile: 32m x 64n
    int lr = lane & 15, kg = lane >> 4;
    int rg = lane >> 4;

    f32x4 acc[2][4];
    #pragma unroll
    for (int m = 0; m < 2; ++m)
        #pragma unroll
        for (int n = 0; n < 4; ++n) acc[m][n] = (f32x4)0.f;

    // ---- phase 1: t = relu(bn1(A @ W1)) ----
    for (int kc = 0; kc < 8; ++kc) {
        int k0 = kc * 32;
        __syncthreads();
        if (tid < 256) {                     // A tile: 64 rows x 32 k
            int r = tid >> 2, k8 = (tid & 3) * 8;
            *(float4*)&As[r][k8] = *(const float4*)(A + (size_t)(m0 + r) * DD + k0 + k8);
        }
        #pragma unroll
        for (int i = 0; i < 2; ++i) {        // W1^T tile: 256 n x 32 k
            int idx = tid + i * 512;
            int r = idx >> 2, k8 = (idx & 3) * 8;
            *(float4*)&Ws[r][k8] = *(const float4*)(W1t + (size_t)r * DD + k0 + k8);
        }
        __syncthreads();
        bf16x8 ah[2], bh[4];
        #pragma unroll
        for (int m = 0; m < 2; ++m)
            ah[m] = *(const bf16x8*)&As[wm * 32 + m * 16 + lr][kg * 8];
        #pragma unroll
        for (int n = 0; n < 4; ++n)
            bh[n] = *(const bf16x8*)&Ws[wn * 64 + n * 16 + lr][kg * 8];
        #pragma unroll
        for (int m = 0; m < 2; ++m)
            #pragma unroll
            for (int n = 0; n < 4; ++n)
                acc[m][n] = __builtin_amdgcn_mfma_f32_16x16x32_bf16(ah[m], bh[n], acc[m][n], 0, 0, 0);
    }
    // epilogue 1: bn1+relu -> Ts (bf16), pair-packed b32 writes (bank-friendly)
    {
        float sN[4], svN[4];
        #pragma unroll
        for (int n = 0; n < 4; ++n) {
            int jj = wn * 64 + n * 16 + lr;
            sN[n]  = g1[jj] * rsqrtf(v1[jj] + EPSV);
            svN[n] = (b1[jj] - m1[jj]) * sN[n] + be1[jj];
        }
        #pragma unroll
        for (int m = 0; m < 2; ++m)
            #pragma unroll
            for (int n = 0; n < 4; ++n) {
                int cc = wn * 64 + n * 16 + lr;
                ushort h[4];
                #pragma unroll
                for (int r = 0; r < 4; ++r) {
                    float y = acc[m][n][r] * sN[n] + svN[n];
                    h[r] = f2bf(y > 0.f ? y : 0.f);
                }
                uint own01 = (uint)h[0] | ((uint)h[1] << 16);
                uint own23 = (uint)h[2] | ((uint)h[3] << 16);
                uint p01 = (uint)__shfl_xor((int)own01, 1);
                uint p23 = (uint)__shfl_xor((int)own23, 1);
                int row0 = wm * 32 + m * 16 + rg * 4;
                if ((lr & 1) == 0) {
                    *(uint*)&Ts[row0 + 0][cc] = (own01 & 0xffffu) | (p01 << 16);
                    *(uint*)&Ts[row0 + 1][cc] = (own01 >> 16) | (p01 & 0xffff0000u);
                } else {
                    *(uint*)&Ts[row0 + 2][cc - 1] = (p23 & 0xffffu) | (own23 << 16);
                    *(uint*)&Ts[row0 + 3][cc - 1] = (p23 >> 16) | (own23 & 0xffff0000u);
                }
            }
    }
    #pragma unroll
    for (int m = 0; m < 2; ++m)
        #pragma unroll
        for (int n = 0; n < 4; ++n) acc[m][n] = (f32x4)0.f;

    // ---- phase 2: h = relu(bn2(t @ W2)), t read from Ts ----
    for (int kc = 0; kc < 8; ++kc) {
        int k0 = kc * 32;
        __syncthreads();                     // Ts complete / Ws reusable
        #pragma unroll
        for (int i = 0; i < 2; ++i) {        // W2^T tile: 256 n x 32 k
            int idx = tid + i * 512;
            int r = idx >> 2, k8 = (idx & 3) * 8;
            *(float4*)&Ws[r][k8] = *(const float4*)(W2t + (size_t)r * DD + k0 + k8);
        }
        __syncthreads();
        bf16x8 ah[2], bh[4];
        #pragma unroll
        for (int m = 0; m < 2; ++m)
            ah[m] = *(const bf16x8*)&Ts[wm * 32 + m * 16 + lr][k0 + kg * 8];
        #pragma unroll
        for (int n = 0; n < 4; ++n)
            bh[n] = *(const bf16x8*)&Ws[wn * 64 + n * 16 + lr][kg * 8];
        #pragma unroll
        for (int m = 0; m < 2; ++m)
            #pragma unroll
            for (int n = 0; n < 4; ++n)
                acc[m][n] = __builtin_amdgcn_mfma_f32_16x16x32_bf16(ah[m], bh[n], acc[m][n], 0, 0, 0);
    }
    __syncthreads();                         // all Ts reads done before overwrite

    // epilogue 2: bn2+relu -> Ts (repack scratch) -> coalesced 16B stores
    {
        float sN[4], svN[4];
        #pragma unroll
        for (int n = 0; n < 4; ++n) {
            int jj = wn * 64 + n * 16 + lr;
            sN[n]  = g2[jj] * rsqrtf(v2[jj] + EPSV);
            svN[n] = (b2[jj] - m2[jj]) * sN[n] + be2[jj];
        }
        #pragma unroll
        for (int m = 0; m < 2; ++m)
            #pragma unroll
            for (int n = 0; n < 4; ++n) {
                int cc = wn * 64 + n * 16 + lr;
                ushort h[4];
                #pragma unroll
                for (int r = 0; r < 4; ++r) {
                    float y = acc[m][n][r] * sN[n] + svN[n];
                    h[r] = f2bf(y > 0.f ? y : 0.f);
                }
                uint own01 = (uint)h[0] | ((uint)h[1] << 16);
                uint own23 = (uint)h[2] | ((uint)h[3] << 16);
                uint p01 = (uint)__shfl_xor((int)own01, 1);
                uint p23 = (uint)__shfl_xor((int)own23, 1);
                int row0 = wm * 32 + m * 16 + rg * 4;
                if ((lr & 1) == 0) {
                    *(uint*)&Ts[row0 + 0][cc] = (own01 & 0xffffu) | (p01 << 16);
                    *(uint*)&Ts[row0 + 1][cc] = (own01 >> 16) | (p01 & 0xffff0000u);
                } else {
                    *(uint*)&Ts[row0 + 2][cc - 1] = (p23 & 0xffffu) | (own23 << 16);
                    *(uint*)&Ts[row0 + 3][cc - 1] = (p23 >> 16) | (own23 & 0xffff0000u);
                }
            }
        // wave-private readback (in-order DS + compiler waitcnt give visibility)
        #pragma unroll
        for (int i = 0; i < 4; ++i) {
            int cid = lane + i * 64;         // 256 chunks: 32 rows x 8 chunks
            int row = cid >> 3, c8 = cid & 7;
            u16x8 vv = *(const u16x8*)&Ts[wm * 32 + row][wn * 64 + c8 * 8];
            *(u16x8*)(O + (size_t)(m0 + wm * 32 + row) * DD + wn * 64 + c8 * 8) = vv;
        }
    }
}

// ---------- layer-0 score: batch-independent; ASSIGNS output ----------
__global__ __launch_bounds__(64) void k_score0(const float4* __restrict__ emo,
                                               const float4* __restrict__ pw,
                                               const float* __restrict__ pb,
                                               float* __restrict__ out)
{
    int q = blockIdx.x, t = threadIdx.x;
    float4 e = emo[q * 64 + t], wv = pw[t];
    float s = e.x * wv.x + e.y * wv.y + e.z * wv.z + e.w * wv.w;
    #pragma unroll
    for (int off = 32; off > 0; off >>= 1) s += __shfl_down(s, off);
    if (t == 0) {
        s += pb[0];
        for (int b = 0; b < BB; ++b) out[b * QQ + q] = s;
    }
}

// ---------- score layers 1..4 ----------
__global__ __launch_bounds__(64) void k_score2(const ushort4* __restrict__ hhi,
                                               const float4* __restrict__ pw,
                                               const float* __restrict__ pb, int l,
                                               float* __restrict__ out)
{
    int bid = blockIdx.x;
    int b = bid / QQ, q = bid % QQ;
    int t = threadIdx.x;
    size_t o = ((size_t)b * NN + q) * 64 + t;
    ushort4 hh = hhi[o];
    float4 wv = pw[l * 64 + t];
    float sum = bf2f(hh.x) * wv.x + bf2f(hh.y) * wv.y +
                bf2f(hh.z) * wv.z + bf2f(hh.w) * wv.w;
    #pragma unroll
    for (int off = 32; off > 0; off >>= 1) sum += __shfl_down(sum, off);
    if (t == 0) out[bid] += sum + pb[l];
}

__global__ void k_sigmoid(float* out)
{
    int i = threadIdx.x + blockIdx.x * blockDim.x;
    if (i < BB * QQ) out[i] = 1.f / (1.f + expf(-out[i]));
}

extern "C" void kernel_launch(void* const* d_in, const int* in_sizes, int n_in,
                              void* d_out, int out_size, void* d_ws, size_t ws_size,
                              hipStream_t stream)
{
    const float* batch = (const float*)d_in[0];
    const int*   edges = (const int*)d_in[1];
    const float* emo   = (const float*)d_in[2];
    const float* w1    = (const float*)d_in[3];
    const float* b1    = (const float*)d_in[4];
    const float* m_g   = (const float*)d_in[5];
    const float* m_b   = (const float*)d_in[6];
    const float* m_m   = (const float*)d_in[7];
    const float* m_v   = (const float*)d_in[8];
    const float* w2    = (const float*)d_in[9];
    const float* b2    = (const float*)d_in[10];
    const float* g_g   = (const float*)d_in[11];
    const float* g_b   = (const float*)d_in[12];
    const float* g_m   = (const float*)d_in[13];
    const float* g_v   = (const float*)d_in[14];
    const float* pw    = (const float*)d_in[15];
    const float* pb    = (const float*)d_in[16];
    float* out = (float*)d_out;

    const size_t HSZ = (size_t)BB * NN * DD;
    const size_t WT  = (size_t)8 * DD * DD;

    ushort* h_hi = (ushort*)d_ws;
    ushort* P_hi = h_hi + HSZ;
    ushort* wt_hi = P_hi + HSZ;
    int* cnt     = (int*)(wt_hi + WT);
    int* row_ptr = cnt + NN;
    int* cursor  = row_ptr + (NN + 4);
    int* col     = cursor + NN;            // 16B-aligned

    const int* src = edges;
    const int* dst = edges + EE;

    hipMemsetAsync(cnt, 0, NN * sizeof(int), stream);
    k_count<<<EE / 256, 256, 0, stream>>>(src, cnt);
    k_scan<<<1, 256, 0, stream>>>(cnt, row_ptr, cursor);
    k_fill<<<EE / 256, 256, 0, stream>>>(src, dst, cursor, col);
    k_wprep<<<512, 256, 0, stream>>>(w1, w2, wt_hi);
    k_prep0<<<4096, 256, 0, stream>>>((const float4*)batch, (const float4*)emo,
                                      (ushort4*)h_hi);
    k_score0<<<QQ, 64, 0, stream>>>((const float4*)emo, (const float4*)pw, pb, out);

    for (int l = 0; l < LL; ++l) {
        k_spmm6<<<8192, 256, 0, stream>>>(h_hi, row_ptr, col, P_hi);
        k_gemm_fused<<<1024, 512, 0, stream>>>(
            P_hi,
            wt_hi + (size_t)l * DD * DD, wt_hi + (size_t)(4 + l) * DD * DD,
            b1 + l * DD, m_g + l * DD, m_b + l * DD, m_m + l * DD, m_v + l * DD,
            b2 + l * DD, g_g + l * DD, g_b + l * DD, g_m + l * DD, g_v + l * DD,
            h_hi);
        k_score2<<<BB * QQ, 64, 0, stream>>>((const ushort4*)h_hi,
                                             (const float4*)pw, pb, l + 1, out);
    }
    k_sigmoid<<<1, 288, 0, stream>>>(out);
}

// Round 11
// 316.731 us; speedup vs baseline: 1.0839x; 1.0839x over previous
//
#include <hip/hip_runtime.h>
#include <hip/hip_bf16.h>

#define NN 2048
#define QQ 9
#define DD 256
#define LL 4
#define BB 32
#define EE 32768
#define EPSV 1e-5f

typedef __attribute__((ext_vector_type(8))) short bf16x8;
typedef __attribute__((ext_vector_type(8))) ushort u16x8;
typedef __attribute__((ext_vector_type(4))) float f32x4;
typedef __attribute__((ext_vector_type(4))) int i32x4;

__device__ __forceinline__ ushort f2bf(float x)
{
    uint u = __float_as_uint(x);
    u += 0x7FFFu + ((u >> 16) & 1u);
    return (ushort)(u >> 16);
}
__device__ __forceinline__ float bf2f(ushort h)
{
    return __uint_as_float(((uint)h) << 16);
}

// ---------- CSR build ----------
__global__ void k_count(const int* __restrict__ src, int* __restrict__ cnt)
{
    int e = blockIdx.x * blockDim.x + threadIdx.x;
    if (e < EE) atomicAdd(&cnt[src[e]], 1);
}

__global__ __launch_bounds__(256) void k_scan(const int* __restrict__ cnt,
                                              int* __restrict__ row_ptr,
                                              int* __restrict__ cursor)
{
    __shared__ int part[256];
    int t = threadIdx.x;
    int local[8];
    int s = 0;
    #pragma unroll
    for (int i = 0; i < 8; ++i) { local[i] = cnt[t * 8 + i]; s += local[i]; }
    part[t] = s;
    __syncthreads();
    for (int off = 1; off < 256; off <<= 1) {
        int v = (t >= off) ? part[t - off] : 0;
        __syncthreads();
        part[t] += v;
        __syncthreads();
    }
    int run = part[t] - s;
    #pragma unroll
    for (int i = 0; i < 8; ++i) {
        int idx = t * 8 + i;
        row_ptr[idx] = run;
        cursor[idx]  = run;
        run += local[i];
    }
    if (t == 255) row_ptr[NN] = run;
}

__global__ void k_fill(const int* __restrict__ src, const int* __restrict__ dst,
                       int* __restrict__ cursor, int* __restrict__ col)
{
    int e = blockIdx.x * blockDim.x + threadIdx.x;
    if (e < EE) {
        int p = atomicAdd(&cursor[src[e]], 1);
        col[p] = dst[e];
    }
}

// ---------- h0 = bf16(batch with rows [0,Q) <- emotion_emb) ----------
__global__ void k_prep0(const float4* __restrict__ bf, const float4* __restrict__ emo,
                        ushort4* __restrict__ hhi)
{
    int total = BB * NN * (DD / 4);
    for (int idx = blockIdx.x * blockDim.x + threadIdx.x; idx < total;
         idx += gridDim.x * blockDim.x) {
        int d4 = idx & 63;
        int n  = (idx >> 6) & (NN - 1);
        float4 v = (n < QQ) ? emo[n * 64 + d4] : bf[idx];
        ushort4 h;
        h.x = f2bf(v.x); h.y = f2bf(v.y); h.z = f2bf(v.z); h.w = f2bf(v.w);
        hhi[idx] = h;
    }
}

// ---------- pooled = h + A.h : batch-paired gather (2 batches per wave) ----------
__global__ __launch_bounds__(256) void k_spmm6(
    const ushort* __restrict__ phi,
    const int* __restrict__ row_ptr, const int* __restrict__ col,
    ushort* __restrict__ ohi)
{
    int x     = blockIdx.x & 7;          // XCD slice: batches [4x, 4x+4)
    int local = blockIdx.x >> 3;
    int w     = threadIdx.x >> 6;
    int t     = threadIdx.x & 63;
    int inst  = local * 4 + w;           // [0, 4096): (pair-of-batches, node)
    int pl    = inst >> 11;              // 0/1: which batch pair in this XCD
    int n     = inst & (NN - 1);
    int b     = x * 4 + pl * 2 + (t >> 5);   // lanes 0-31: batch b0; 32-63: b0+1
    int q     = t & 31;                  // 16B chunk: elems [8q, 8q+8)
    const ushort* base = phi + (size_t)b * NN * DD + q * 8;

    u16x8 sv = *(const u16x8*)(base + (size_t)n * DD);
    float a[8];
    #pragma unroll
    for (int k = 0; k < 8; ++k) a[k] = bf2f((ushort)sv[k]);

    int beg = row_ptr[n], end = row_ptr[n + 1];
    int j = beg;
    for (; j < end && (j & 3); ++j) {
        u16x8 g = *(const u16x8*)(base + (size_t)col[j] * DD);
        #pragma unroll
        for (int k = 0; k < 8; ++k) a[k] += bf2f((ushort)g[k]);
    }
    for (; j + 8 <= end; j += 8) {
        i32x4 c0 = *(const i32x4*)(col + j);
        i32x4 c1 = *(const i32x4*)(col + j + 4);
        u16x8 g[8];
        g[0] = *(const u16x8*)(base + (size_t)c0.x * DD);
        g[1] = *(const u16x8*)(base + (size_t)c0.y * DD);
        g[2] = *(const u16x8*)(base + (size_t)c0.z * DD);
        g[3] = *(const u16x8*)(base + (size_t)c0.w * DD);
        g[4] = *(const u16x8*)(base + (size_t)c1.x * DD);
        g[5] = *(const u16x8*)(base + (size_t)c1.y * DD);
        g[6] = *(const u16x8*)(base + (size_t)c1.z * DD);
        g[7] = *(const u16x8*)(base + (size_t)c1.w * DD);
        #pragma unroll
        for (int u = 0; u < 8; ++u)
            #pragma unroll
            for (int k = 0; k < 8; ++k) a[k] += bf2f((ushort)g[u][k]);
    }
    if (j + 4 <= end) {
        i32x4 c = *(const i32x4*)(col + j);
        u16x8 g[4];
        g[0] = *(const u16x8*)(base + (size_t)c.x * DD);
        g[1] = *(const u16x8*)(base + (size_t)c.y * DD);
        g[2] = *(const u16x8*)(base + (size_t)c.z * DD);
        g[3] = *(const u16x8*)(base + (size_t)c.w * DD);
        #pragma unroll
        for (int u = 0; u < 4; ++u)
            #pragma unroll
            for (int k = 0; k < 8; ++k) a[k] += bf2f((ushort)g[u][k]);
        j += 4;
    }
    for (; j < end; ++j) {
        u16x8 g = *(const u16x8*)(base + (size_t)col[j] * DD);
        #pragma unroll
        for (int k = 0; k < 8; ++k) a[k] += bf2f((ushort)g[k]);
    }

    u16x8 o;
    #pragma unroll
    for (int k = 0; k < 8; ++k) o[k] = f2bf(a[k]);
    *(u16x8*)(ohi + ((size_t)b * NN + n) * DD + q * 8) = o;
}

// ---------- weight prep: Wt[mat][n][k] = bf16(W[mat][k][n]) ----------
__global__ __launch_bounds__(256) void k_wprep(const float* __restrict__ w1,
                                               const float* __restrict__ w2,
                                               ushort* __restrict__ wt_hi)
{
    __shared__ float tile[32][36];
    int bx = blockIdx.x;
    int mat = bx >> 6;
    int tt  = bx & 63;
    int tk = (tt >> 3) * 32;
    int tn = (tt & 7) * 32;
    const float* src = (mat < 4) ? (w1 + (size_t)mat * DD * DD)
                                 : (w2 + (size_t)(mat - 4) * DD * DD);
    int t = threadIdx.x;
    int r = t >> 3, c0 = (t & 7) * 4;
    float4 v = *(const float4*)(src + (size_t)(tk + r) * DD + tn + c0);
    tile[r][c0 + 0] = v.x; tile[r][c0 + 1] = v.y;
    tile[r][c0 + 2] = v.z; tile[r][c0 + 3] = v.w;
    __syncthreads();
    int nn = t >> 3, kq = (t & 7) * 4;
    ushort4 hh;
    hh.x = f2bf(tile[kq + 0][nn]); hh.y = f2bf(tile[kq + 1][nn]);
    hh.z = f2bf(tile[kq + 2][nn]); hh.w = f2bf(tile[kq + 3][nn]);
    size_t off = (size_t)mat * DD * DD + (size_t)(tn + nn) * DD + tk + kq;
    *(ushort4*)(wt_hi + off) = hh;
}

// ---------- fused layer GEMM + score: h = relu(bn2( relu(bn1(P@W1)) @ W2 )) ----------
// 64 rows x 256 N per block, 4 waves (32m x 128n). Double-buffered unpadded
// staging tiles (zero-conflict fragment reads), one barrier per K-step,
// next K-slice loads issued after the barrier so latency hides under MFMA.
__global__ __launch_bounds__(256, 2) void k_gemm_fused(
    const ushort* __restrict__ A, const ushort* __restrict__ W1t,
    const ushort* __restrict__ W2t,
    const float* __restrict__ b1, const float* __restrict__ g1,
    const float* __restrict__ be1, const float* __restrict__ m1,
    const float* __restrict__ v1,
    const float* __restrict__ b2, const float* __restrict__ g2,
    const float* __restrict__ be2, const float* __restrict__ m2,
    const float* __restrict__ v2,
    const float* __restrict__ pw, const float* __restrict__ pb, int l,
    ushort* __restrict__ O, float* __restrict__ out)
{
    __shared__ alignas(16) ushort As[2][64 * 32];    //  8,192 B
    __shared__ alignas(16) ushort Ws[2][256 * 32];   // 32,768 B
    __shared__ alignas(16) ushort Ts[64][264];       // 33,792 B

    int tid = threadIdx.x;
    int x  = blockIdx.x & 7;                 // XCD-aligned with spmm partition
    int lm = blockIdx.x >> 3;
    int m0 = x * 8192 + lm * 64;
    int lane = tid & 63;
    int w = tid >> 6;                        // 4 waves
    int wm = w & 1, wn = w >> 1;             // wave tile: 32m x 128n
    int lr = lane & 15, kg = lane >> 4;
    int rg = lane >> 4;

    // staging thread mapping
    int ar = tid >> 2, ak = (tid & 3) * 8;   // A: 64 rows x 4 chunks
    const ushort* Ab = A + (size_t)(m0 + ar) * DD + ak;

    f32x4 acc[2][8];
    #pragma unroll
    for (int m = 0; m < 2; ++m)
        #pragma unroll
        for (int n = 0; n < 8; ++n) acc[m][n] = (f32x4)0.f;

    // ---- phase 1: t = relu(bn1(A @ W1)) ----
    float4 rA;
    float4 rW[4];
    rA = *(const float4*)(Ab);
    #pragma unroll
    for (int i = 0; i < 4; ++i) {
        int idx = tid + i * 256;
        int r = idx >> 2, k8 = (idx & 3) * 8;
        rW[i] = *(const float4*)(W1t + (size_t)r * DD + k8);
    }
    int cur = 0;
    for (int kc = 0; kc < 8; ++kc) {
        // commit staged regs to buffer `cur`
        *(float4*)&As[cur][ar * 32 + ak] = rA;
        #pragma unroll
        for (int i = 0; i < 4; ++i) {
            int idx = tid + i * 256;
            int r = idx >> 2, k8 = (idx & 3) * 8;
            *(float4*)&Ws[cur][r * 32 + k8] = rW[i];
        }
        __syncthreads();
        // issue next K-slice loads (in flight during MFMA below)
        if (kc < 7) {
            int k0n = (kc + 1) * 32;
            rA = *(const float4*)(Ab + k0n);
            #pragma unroll
            for (int i = 0; i < 4; ++i) {
                int idx = tid + i * 256;
                int r = idx >> 2, k8 = (idx & 3) * 8;
                rW[i] = *(const float4*)(W1t + (size_t)r * DD + k0n + k8);
            }
        }
        bf16x8 ah[2], bh[8];
        #pragma unroll
        for (int m = 0; m < 2; ++m)
            ah[m] = *(const bf16x8*)&As[cur][(wm * 32 + m * 16 + lr) * 32 + kg * 8];
        #pragma unroll
        for (int n = 0; n < 8; ++n)
            bh[n] = *(const bf16x8*)&Ws[cur][(wn * 128 + n * 16 + lr) * 32 + kg * 8];
        #pragma unroll
        for (int m = 0; m < 2; ++m)
            #pragma unroll
            for (int n = 0; n < 8; ++n)
                acc[m][n] = __builtin_amdgcn_mfma_f32_16x16x32_bf16(ah[m], bh[n], acc[m][n], 0, 0, 0);
        cur ^= 1;
    }
    // epilogue 1: bn1+relu -> Ts (bf16)
    {
        float sN[8], svN[8];
        #pragma unroll
        for (int n = 0; n < 8; ++n) {
            int jj = wn * 128 + n * 16 + lr;
            sN[n]  = g1[jj] * rsqrtf(v1[jj] + EPSV);
            svN[n] = (b1[jj] - m1[jj]) * sN[n] + be1[jj];
        }
        #pragma unroll
        for (int m = 0; m < 2; ++m)
            #pragma unroll
            for (int n = 0; n < 8; ++n) {
                int cc = wn * 128 + n * 16 + lr;
                #pragma unroll
                for (int r = 0; r < 4; ++r) {
                    float y = acc[m][n][r] * sN[n] + svN[n];
                    Ts[wm * 32 + m * 16 + rg * 4 + r][cc] = f2bf(y > 0.f ? y : 0.f);
                }
            }
    }
    #pragma unroll
    for (int m = 0; m < 2; ++m)
        #pragma unroll
        for (int n = 0; n < 8; ++n) acc[m][n] = (f32x4)0.f;

    __syncthreads();                         // Ts visible; Ws buffers free

    // ---- phase 2: h = relu(bn2(t @ W2)), t from Ts ----
    #pragma unroll
    for (int i = 0; i < 4; ++i) {
        int idx = tid + i * 256;
        int r = idx >> 2, k8 = (idx & 3) * 8;
        rW[i] = *(const float4*)(W2t + (size_t)r * DD + k8);
    }
    cur = 0;
    for (int kc = 0; kc < 8; ++kc) {
        #pragma unroll
        for (int i = 0; i < 4; ++i) {
            int idx = tid + i * 256;
            int r = idx >> 2, k8 = (idx & 3) * 8;
            *(float4*)&Ws[cur][r * 32 + k8] = rW[i];
        }
        __syncthreads();
        if (kc < 7) {
            int k0n = (kc + 1) * 32;
            #pragma unroll
            for (int i = 0; i < 4; ++i) {
                int idx = tid + i * 256;
                int r = idx >> 2, k8 = (idx & 3) * 8;
                rW[i] = *(const float4*)(W2t + (size_t)r * DD + k0n + k8);
            }
        }
        bf16x8 ah[2], bh[8];
        #pragma unroll
        for (int m = 0; m < 2; ++m)
            ah[m] = *(const bf16x8*)&Ts[wm * 32 + m * 16 + lr][kc * 32 + kg * 8];
        #pragma unroll
        for (int n = 0; n < 8; ++n)
            bh[n] = *(const bf16x8*)&Ws[cur][(wn * 128 + n * 16 + lr) * 32 + kg * 8];
        #pragma unroll
        for (int m = 0; m < 2; ++m)
            #pragma unroll
            for (int n = 0; n < 8; ++n)
                acc[m][n] = __builtin_amdgcn_mfma_f32_16x16x32_bf16(ah[m], bh[n], acc[m][n], 0, 0, 0);
        cur ^= 1;
    }
    __syncthreads();                         // all Ts reads done before overwrite

    // epilogue 2: bn2+relu -> Ts (repack scratch) -> coalesced 16B stores
    {
        float sN[8], svN[8];
        #pragma unroll
        for (int n = 0; n < 8; ++n) {
            int jj = wn * 128 + n * 16 + lr;
            sN[n]  = g2[jj] * rsqrtf(v2[jj] + EPSV);
            svN[n] = (b2[jj] - m2[jj]) * sN[n] + be2[jj];
        }
        #pragma unroll
        for (int m = 0; m < 2; ++m)
            #pragma unroll
            for (int n = 0; n < 8; ++n) {
                int cc = wn * 128 + n * 16 + lr;
                #pragma unroll
                for (int r = 0; r < 4; ++r) {
                    float y = acc[m][n][r] * sN[n] + svN[n];
                    Ts[wm * 32 + m * 16 + rg * 4 + r][cc] = f2bf(y > 0.f ? y : 0.f);
                }
            }
        // wave-private readback (in-order DS + compiler waitcnt give visibility)
        #pragma unroll
        for (int i = 0; i < 8; ++i) {
            int cid = lane + i * 64;         // 512 chunks: 32 rows x 16 chunks
            int row = cid >> 4, c8 = cid & 15;
            u16x8 vv = *(const u16x8*)&Ts[wm * 32 + row][wn * 128 + c8 * 8];
            *(u16x8*)(O + (size_t)(m0 + wm * 32 + row) * DD + wn * 128 + c8 * 8) = vv;
        }
    }

    // ---- fused score (+ sigmoid at last layer) for the block owning rows 0-63 ----
    __syncthreads();                         // all waves' Ts h-values visible
    if ((m0 & (NN - 1)) == 0) {
        int b = m0 >> 11;
        for (int q = w; q < QQ; q += 4) {
            ushort4 hv = *(const ushort4*)&Ts[q][lane * 4];
            const float4 wv = *(const float4*)&pw[(l + 1) * DD + lane * 4];
            float s = bf2f(hv.x) * wv.x + bf2f(hv.y) * wv.y +
                      bf2f(hv.z) * wv.z + bf2f(hv.w) * wv.w;
            #pragma unroll
            for (int off = 32; off > 0; off >>= 1) s += __shfl_down(s, off);
            if (lane == 0) {
                float v = out[b * QQ + q] + s + pb[l + 1];
                out[b * QQ + q] = (l == LL - 1) ? 1.f / (1.f + expf(-v)) : v;
            }
        }
    }
}

// ---------- layer-0 score: batch-independent; ASSIGNS output ----------
__global__ __launch_bounds__(64) void k_score0(const float4* __restrict__ emo,
                                               const float4* __restrict__ pw,
                                               const float* __restrict__ pb,
                                               float* __restrict__ out)
{
    int q = blockIdx.x, t = threadIdx.x;
    float4 e = emo[q * 64 + t], wv = pw[t];
    float s = e.x * wv.x + e.y * wv.y + e.z * wv.z + e.w * wv.w;
    #pragma unroll
    for (int off = 32; off > 0; off >>= 1) s += __shfl_down(s, off);
    if (t == 0) {
        s += pb[0];
        for (int b = 0; b < BB; ++b) out[b * QQ + q] = s;
    }
}

extern "C" void kernel_launch(void* const* d_in, const int* in_sizes, int n_in,
                              void* d_out, int out_size, void* d_ws, size_t ws_size,
                              hipStream_t stream)
{
    const float* batch = (const float*)d_in[0];
    const int*   edges = (const int*)d_in[1];
    const float* emo   = (const float*)d_in[2];
    const float* w1    = (const float*)d_in[3];
    const float* b1    = (const float*)d_in[4];
    const float* m_g   = (const float*)d_in[5];
    const float* m_b   = (const float*)d_in[6];
    const float* m_m   = (const float*)d_in[7];
    const float* m_v   = (const float*)d_in[8];
    const float* w2    = (const float*)d_in[9];
    const float* b2    = (const float*)d_in[10];
    const float* g_g   = (const float*)d_in[11];
    const float* g_b   = (const float*)d_in[12];
    const float* g_m   = (const float*)d_in[13];
    const float* g_v   = (const float*)d_in[14];
    const float* pw    = (const float*)d_in[15];
    const float* pb    = (const float*)d_in[16];
    float* out = (float*)d_out;

    const size_t HSZ = (size_t)BB * NN * DD;
    const size_t WT  = (size_t)8 * DD * DD;

    ushort* h_hi = (ushort*)d_ws;
    ushort* P_hi = h_hi + HSZ;
    ushort* wt_hi = P_hi + HSZ;
    int* cnt     = (int*)(wt_hi + WT);
    int* row_ptr = cnt + NN;
    int* cursor  = row_ptr + (NN + 4);
    int* col     = cursor + NN;            // 16B-aligned

    const int* src = edges;
    const int* dst = edges + EE;

    hipMemsetAsync(cnt, 0, NN * sizeof(int), stream);
    k_count<<<EE / 256, 256, 0, stream>>>(src, cnt);
    k_scan<<<1, 256, 0, stream>>>(cnt, row_ptr, cursor);
    k_fill<<<EE / 256, 256, 0, stream>>>(src, dst, cursor, col);
    k_wprep<<<512, 256, 0, stream>>>(w1, w2, wt_hi);
    k_prep0<<<4096, 256, 0, stream>>>((const float4*)batch, (const float4*)emo,
                                      (ushort4*)h_hi);
    k_score0<<<QQ, 64, 0, stream>>>((const float4*)emo, (const float4*)pw, pb, out);

    for (int l = 0; l < LL; ++l) {
        k_spmm6<<<8192, 256, 0, stream>>>(h_hi, row_ptr, col, P_hi);
        k_gemm_fused<<<1024, 256, 0, stream>>>(
            P_hi,
            wt_hi + (size_t)l * DD * DD, wt_hi + (size_t)(4 + l) * DD * DD,
            b1 + l * DD, m_g + l * DD, m_b + l * DD, m_m + l * DD, m_v + l * DD,
            b2 + l * DD, g_g + l * DD, g_b + l * DD, g_m + l * DD, g_v + l * DD,
            pw, pb, l,
            h_hi, out);
    }
}